// Round 11
// baseline (258.879 us; speedup 1.0000x reference)
//
#include <hip/hip_runtime.h>
#include <hip/hip_bf16.h>

#define BB  64
#define JJ  2048
#define DI  16
#define KC  32
#define DOO 32
#define NKO 1024   // KC*DOO

typedef __bf16 bf16;
typedef __attribute__((ext_vector_type(8)))  __bf16 bf16x8;
typedef __attribute__((ext_vector_type(4)))  __bf16 bf16x4;
typedef __attribute__((ext_vector_type(2)))  __bf16 bf16x2;
typedef __attribute__((ext_vector_type(4)))  float  f32x4;
typedef __attribute__((ext_vector_type(16))) float  f32x16;

// ======== 32x32x16 MFMA scheme ========
// D = A(32x16) * B(16x32).  A = W-slice (rows = o), B = X (cols = b). K = i (16).
// A-frag: lane l holds row o = l&31, k i = (l>>5)*8 + e
// B-frag: lane l holds col b = l&31, k i = (l>>5)*8 + e
// C/D   : col b = lane&31, row o = (reg&3) + 8*(reg>>2) + 4*(lane>>5)   [m74/m101]

// ---------------- prep: X f32 [B][J][Di] -> B-fragment layout ----------------
__global__ __launch_bounds__(256)
void prep_x3(const float* __restrict__ X, bf16* __restrict__ Xfrag)
{
    int flat = blockIdx.x * 256 + threadIdx.x;    // < 262144
    int lane = flat & 63;
    int c01  = (flat >> 6) & 1;
    int j    = flat >> 7;
    int b    = c01 * 32 + (lane & 31);
    int i0   = (lane >> 5) * 8;
    const float* src = X + ((size_t)b * JJ + j) * DI + i0;
    bf16x8 o8;
#pragma unroll
    for (int e = 0; e < 8; ++e) o8[e] = (bf16)src[e];
    *reinterpret_cast<bf16x8*>(Xfrag + (size_t)flat * 8) = o8;
}

// XCD-aware decodes (bijective for the grids used).
__device__ __forceinline__ void decode_qjr(int id, int& q, int& jr)   // grid 4P, P%8==0
{
    q = (id >> 3) & 3; jr = ((id >> 5) << 3) | (id & 7);
}
__device__ __forceinline__ void decode_q8(int id, int& q8, int& jr)   // grid 8P, P%8==0
{
    q8 = (id >> 3) & 7; jr = ((id >> 6) << 3) | (id & 7);
}
__device__ __forceinline__ int decode_jg(int id)    // grid 1024
{
    return (id & 7) * 128 + (id >> 3);
}
__device__ __forceinline__ int decode_j2048(int id) // grid 2048
{
    return (id & 7) * 256 + (id >> 3);
}

// ---------------- fused prep+init, 2-j batched: one latency exposure per 2 j's ----------------
// Block 512 = 8 waves, grid 8P. unit = q8*8 + w = c01*32 + k. c01==0 waves emit Wfrag.
__global__ __launch_bounds__(512, 6)
void caps_init8(const bf16* __restrict__ Xfrag, const float* __restrict__ Wg,
                bf16* __restrict__ Wfrag, bf16* __restrict__ partial, int Jc)
{
    const int tid  = threadIdx.x;
    const int w    = tid >> 6;
    const int lane = tid & 63;
    const int o31  = lane & 31;
    const int hi   = lane >> 5;
    int q8, jr; decode_q8(blockIdx.x, q8, jr);
    const int unit = q8 * 8 + w;
    const int k    = unit & 31;
    const int c01  = unit >> 5;

    f32x16 acc = {};

    const int j0 = jr * Jc;
    int jend = j0 + Jc; if (jend > JJ) jend = JJ;

    int j = j0;
    for (; j + 1 < jend; j += 2) {
        const float* ws0 = Wg + (size_t)j * 16384 + (size_t)k * 512 + hi * 256 + o31;
        const float* ws1 = ws0 + 16384;
        float a0[8], a1[8];
#pragma unroll
        for (int e = 0; e < 8; ++e) a0[e] = ws0[e * 32];
#pragma unroll
        for (int e = 0; e < 8; ++e) a1[e] = ws1[e * 32];
        bf16x8 fw0, fw1;
#pragma unroll
        for (int e = 0; e < 8; ++e) { fw0[e] = (bf16)a0[e]; fw1[e] = (bf16)a1[e]; }
        if (c01 == 0) {
            *reinterpret_cast<bf16x8*>(Wfrag + (((size_t)j * 32 + k) * 64 + lane) * 8)       = fw0;
            *reinterpret_cast<bf16x8*>(Wfrag + (((size_t)(j + 1) * 32 + k) * 64 + lane) * 8) = fw1;
        }
        bf16x8 fx0 = *reinterpret_cast<const bf16x8*>(Xfrag + (((size_t)j * 2 + c01) * 64 + lane) * 8);
        bf16x8 fx1 = *reinterpret_cast<const bf16x8*>(Xfrag + (((size_t)(j + 1) * 2 + c01) * 64 + lane) * 8);
        acc = __builtin_amdgcn_mfma_f32_32x32x16_bf16(fw0, fx0, acc, 0, 0, 0);
        acc = __builtin_amdgcn_mfma_f32_32x32x16_bf16(fw1, fx1, acc, 0, 0, 0);
    }
    for (; j < jend; ++j) {   // tail (odd Jc)
        const float* ws = Wg + (size_t)j * 16384 + (size_t)k * 512 + hi * 256 + o31;
        bf16x8 fw;
#pragma unroll
        for (int e = 0; e < 8; ++e) fw[e] = (bf16)ws[e * 32];
        if (c01 == 0)
            *reinterpret_cast<bf16x8*>(Wfrag + (((size_t)j * 32 + k) * 64 + lane) * 8) = fw;
        bf16x8 fx = *reinterpret_cast<const bf16x8*>(Xfrag + (((size_t)j * 2 + c01) * 64 + lane) * 8);
        acc = __builtin_amdgcn_mfma_f32_32x32x16_bf16(fw, fx, acc, 0, 0, 0);
    }

    bf16* pout = partial + (size_t)jr * (BB * NKO);
#pragma unroll
    for (int qq = 0; qq < 4; ++qq) {
        bf16x4 o4;
#pragma unroll
        for (int rr = 0; rr < 4; ++rr) o4[rr] = (bf16)(acc[qq * 4 + rr] * 0.03125f);
        *reinterpret_cast<bf16x4*>(pout + (((size_t)unit * 4 + qq) * 64 + lane) * 4) = o4;
    }
}

// ---------------- accum, 2-deep software pipeline ----------------
// Block 512 = 8 waves, grid 8P. Next j's fx/fw/cw issued before current MFMA+FMA.
__global__ __launch_bounds__(512, 6)
void caps_accum2(const bf16* __restrict__ Xfrag, const bf16* __restrict__ Wfrag,
                 const float* __restrict__ cbuf, bf16* __restrict__ partial, int Jc)
{
    const int tid  = threadIdx.x;
    const int w    = tid >> 6;
    const int lane = tid & 63;
    const int o31  = lane & 31;
    int q8, jr; decode_q8(blockIdx.x, q8, jr);
    const int unit = q8 * 8 + w;
    const int k    = unit & 31;
    const int c01  = unit >> 5;
    const int b    = c01 * 32 + o31;

    const f32x16 ZV16 = {};
    f32x16 acc = ZV16;

    const int j0 = jr * Jc;
    int jend = j0 + Jc; if (jend > JJ) jend = JJ;

    auto ldx = [&](int j) {
        return *reinterpret_cast<const bf16x8*>(Xfrag + (((size_t)j * 2 + c01) * 64 + lane) * 8);
    };
    auto ldw = [&](int j) {
        return *reinterpret_cast<const bf16x8*>(Wfrag + (((size_t)j * 32 + k) * 64 + lane) * 8);
    };
    auto ldc = [&](int j) {
        return cbuf[((size_t)j * 32 + k) * 64 + b];
    };

    bf16x8 fx = ldx(j0), fw = ldw(j0);
    float  cw = ldc(j0);

    for (int j = j0; j < jend; ++j) {
        const int jn = (j + 1 < jend) ? j + 1 : j;
        bf16x8 nfx = ldx(jn);
        bf16x8 nfw = ldw(jn);
        float  ncw = ldc(jn);
        f32x16 h = __builtin_amdgcn_mfma_f32_32x32x16_bf16(fw, fx, ZV16, 0, 0, 0);
#pragma unroll
        for (int r = 0; r < 16; ++r) acc[r] += cw * h[r];
        fx = nfx; fw = nfw; cw = ncw;
    }

    bf16* pout = partial + (size_t)jr * (BB * NKO);
#pragma unroll
    for (int qq = 0; qq < 4; ++qq) {
        bf16x4 o4;
#pragma unroll
        for (int rr = 0; rr < 4; ++rr) o4[rr] = (bf16)(acc[qq * 4 + rr]);
        *reinterpret_cast<bf16x4*>(pout + (((size_t)unit * 4 + qq) * 64 + lane) * 4) = o4;
    }
}

// ---------------- logits, group-of-4 fw prefetch ----------------
// Block 256 = 4 waves = (c01, kh); grid 2048 (one j per block). Softmax lane-local.
__global__ __launch_bounds__(256, 6)
void caps_logits7(const bf16* __restrict__ Xfrag, const bf16* __restrict__ Wfrag,
                  const float* __restrict__ vsum, float* __restrict__ cbuf)
{
    __shared__ float lex[2][32][32];    // [c01][k][b31]

    const int tid  = threadIdx.x;
    const int wv   = tid >> 6;
    const int lane = tid & 63;
    const int b31  = lane & 31;
    const int hi   = lane >> 5;
    const int c01  = wv & 1;
    const int kh   = wv >> 1;
    const int j    = decode_j2048(blockIdx.x);
    const int b    = c01 * 32 + b31;

    const f32x16 ZV16 = {};

    bf16x8 fx = *reinterpret_cast<const bf16x8*>(Xfrag + (((size_t)j * 2 + c01) * 64 + lane) * 8);
    const bf16*  wfp = Wfrag + (((size_t)j * 32 + kh * 16) * 64 + lane) * 8;
    const float* vb  = vsum + (size_t)b * NKO + (size_t)(kh * 16) * 32 + hi * 4;

    float lk[16];
#pragma unroll
    for (int grp = 0; grp < 4; ++grp) {
        // 4 independent fragment loads in flight
        bf16x8 f0 = *reinterpret_cast<const bf16x8*>(wfp + (grp * 4 + 0) * 512);
        bf16x8 f1 = *reinterpret_cast<const bf16x8*>(wfp + (grp * 4 + 1) * 512);
        bf16x8 f2 = *reinterpret_cast<const bf16x8*>(wfp + (grp * 4 + 2) * 512);
        bf16x8 f3 = *reinterpret_cast<const bf16x8*>(wfp + (grp * 4 + 3) * 512);
#pragma unroll
        for (int t = 0; t < 4; ++t) {
            bf16x8 ft = (t == 0) ? f0 : (t == 1) ? f1 : (t == 2) ? f2 : f3;
            f32x16 h = __builtin_amdgcn_mfma_f32_32x32x16_bf16(ft, fx, ZV16, 0, 0, 0);
            const float* vk = vb + (grp * 4 + t) * 32;
            float a = 0.f;
#pragma unroll
            for (int qq = 0; qq < 4; ++qq) {
                float4 v4 = *reinterpret_cast<const float4*>(vk + qq * 8);
                a += h[qq * 4 + 0] * v4.x + h[qq * 4 + 1] * v4.y
                   + h[qq * 4 + 2] * v4.z + h[qq * 4 + 3] * v4.w;
            }
            a += __shfl_xor(a, 32, 64);
            lk[grp * 4 + t] = a;
        }
    }

    if (hi == 0) {
#pragma unroll
        for (int kk = 0; kk < 16; ++kk) lex[c01][kh * 16 + kk][b31] = lk[kk];
    }
    __syncthreads();

    // merge partner half, lane-local softmax
    float mx = lk[0];
#pragma unroll
    for (int kk = 1; kk < 16; ++kk) mx = fmaxf(mx, lk[kk]);
    float oth[16];
#pragma unroll
    for (int kk = 0; kk < 16; ++kk) {
        oth[kk] = lex[c01][(kh ^ 1) * 16 + kk][b31];
        mx = fmaxf(mx, oth[kk]);
    }
    float sm = 0.f;
#pragma unroll
    for (int kk = 0; kk < 16; ++kk) {
        lk[kk] = __expf(lk[kk] - mx);
        sm += lk[kk] + __expf(oth[kk] - mx);
    }
    float inv = 1.0f / sm;
    __syncthreads();

    if (hi == 0) {
#pragma unroll
        for (int kk = 0; kk < 16; ++kk) lex[c01][kh * 16 + kk][b31] = lk[kk] * inv;
    }
    __syncthreads();

    float* cj = cbuf + (size_t)j * 2048;
#pragma unroll
    for (int it = 0; it < 8; ++it) {
        int idx = it * 256 + tid;
        int kq = idx >> 6, bf = idx & 63;
        cj[idx] = lex[bf >> 5][kq][bf & 31];
    }
}

// ---------------- fallback kernels (raw f32 path, unchanged) ----------------
template<int UF, int MODE>
__global__ __launch_bounds__(1024, 8)
void caps_mm32(const bf16* __restrict__ Xfrag, const bf16* __restrict__ Wfrag,
               const float* __restrict__ Xf, const float* __restrict__ Wf,
               const float* __restrict__ cbuf, bf16* __restrict__ partial, int Jc)
{
    const int tid  = threadIdx.x;
    const int w    = tid >> 6;
    const int lane = tid & 63;
    const int o31  = lane & 31;
    const int hi   = lane >> 5;
    int q, jr; decode_qjr(blockIdx.x, q, jr);
    const int unit = q * 16 + w;
    const int k    = unit & 31;
    const int c01  = unit >> 5;
    const int b    = c01 * 32 + o31;

    const f32x16 ZV16 = {};
    f32x16 acc = ZV16;

    const int j0 = jr * Jc;
    int jend = j0 + Jc; if (jend > JJ) jend = JJ;

    for (int j = j0; j < jend; ++j) {
        bf16x8 fx, fw;
        if constexpr (UF) {
            fx = *reinterpret_cast<const bf16x8*>(Xfrag + (((size_t)j * 2 + c01) * 64 + lane) * 8);
            fw = *reinterpret_cast<const bf16x8*>(Wfrag + (((size_t)j * 32 + k) * 64 + lane) * 8);
        } else {
            const float* xs = Xf + ((size_t)b * JJ + j) * DI + hi * 8;
#pragma unroll
            for (int e = 0; e < 8; ++e) fx[e] = (bf16)xs[e];
            const float* ws = Wf + (size_t)j * 16384 + (size_t)k * 512 + hi * 256 + o31;
#pragma unroll
            for (int e = 0; e < 8; ++e) fw[e] = (bf16)ws[e * 32];
        }
        if constexpr (MODE == 0) {
            acc = __builtin_amdgcn_mfma_f32_32x32x16_bf16(fw, fx, acc, 0, 0, 0);
        } else {
            float cw = cbuf[((size_t)j * 32 + k) * 64 + b];
            f32x16 h = __builtin_amdgcn_mfma_f32_32x32x16_bf16(fw, fx, ZV16, 0, 0, 0);
#pragma unroll
            for (int r = 0; r < 16; ++r) acc[r] += cw * h[r];
        }
    }

    const float esc = (MODE == 0) ? 0.03125f : 1.0f;
    bf16* pout = partial + (size_t)jr * (BB * NKO);
#pragma unroll
    for (int qq = 0; qq < 4; ++qq) {
        bf16x4 o4;
#pragma unroll
        for (int rr = 0; rr < 4; ++rr) o4[rr] = (bf16)(acc[qq * 4 + rr] * esc);
        *reinterpret_cast<bf16x4*>(pout + (((size_t)unit * 4 + qq) * 64 + lane) * 4) = o4;
    }
}

template<int UF>
__global__ __launch_bounds__(256, 6)
void caps_logits32(const bf16* __restrict__ Xfrag, const bf16* __restrict__ Wfrag,
                   const float* __restrict__ Xf, const float* __restrict__ Wf,
                   const float* __restrict__ vsum, float* __restrict__ cbuf)
{
    __shared__ float cl[2][64][33];

    const int tid  = threadIdx.x;
    const int w    = tid >> 6;
    const int lane = tid & 63;
    const int o31  = lane & 31;
    const int hi   = lane >> 5;
    const int jg   = decode_jg(blockIdx.x);
    const int j0   = jg * 2;
    const int jj   = w >> 1;
    const int c01  = w & 1;
    const int j    = j0 + jj;
    const int b    = c01 * 32 + o31;

    const f32x16 ZV16 = {};

    bf16x8 fx;
    if constexpr (UF) {
        fx = *reinterpret_cast<const bf16x8*>(Xfrag + (((size_t)j * 2 + c01) * 64 + lane) * 8);
    } else {
        const float* xs = Xf + ((size_t)b * JJ + j) * DI + hi * 8;
#pragma unroll
        for (int e = 0; e < 8; ++e) fx[e] = (bf16)xs[e];
    }

    const float* vb = vsum + (size_t)b * NKO + hi * 4;
    float lk[32];
#pragma unroll
    for (int k = 0; k < 32; ++k) {
        bf16x8 fw;
        if constexpr (UF) {
            fw = *reinterpret_cast<const bf16x8*>(Wfrag + (((size_t)j * 32 + k) * 64 + lane) * 8);
        } else {
            const float* ws = Wf + (size_t)j * 16384 + (size_t)k * 512 + hi * 256 + o31;
#pragma unroll
            for (int e = 0; e < 8; ++e) fw[e] = (bf16)ws[e * 32];
        }
        f32x16 h = __builtin_amdgcn_mfma_f32_32x32x16_bf16(fw, fx, ZV16, 0, 0, 0);
        float a = 0.f;
        const float* vk = vb + k * 32;
#pragma unroll
        for (int qq = 0; qq < 4; ++qq) {
            float4 v4 = *reinterpret_cast<const float4*>(vk + qq * 8);
            a += h[qq * 4 + 0] * v4.x + h[qq * 4 + 1] * v4.y
               + h[qq * 4 + 2] * v4.z + h[qq * 4 + 3] * v4.w;
        }
        a += __shfl_xor(a, 32, 64);
        lk[k] = a;
    }

    float mx = lk[0];
#pragma unroll
    for (int k = 1; k < 32; ++k) mx = fmaxf(mx, lk[k]);
    float sm = 0.f;
#pragma unroll
    for (int k = 0; k < 32; ++k) { lk[k] = __expf(lk[k] - mx); sm += lk[k]; }
    float inv = 1.0f / sm;

    if (hi == 0) {
#pragma unroll
        for (int k = 0; k < 32; ++k) cl[jj][b][k] = lk[k] * inv;
    }
    __syncthreads();

#pragma unroll
    for (int j2 = 0; j2 < 2; ++j2) {
#pragma unroll
        for (int i = 0; i < 8; ++i) {
            int idx = i * 256 + tid;
            int kk = idx >> 6, bb = idx & 63;
            cbuf[((size_t)(j0 + j2) * 32 + kk) * 64 + bb] = cl[j2][bb][kk];
        }
    }
}

// ---------------- reduce stage 1: sum P slices in 8 groups -> tmp f32 [8][65536] ----------------
__global__ __launch_bounds__(256)
void caps_r1(const bf16* __restrict__ partial, float* __restrict__ tmp, int P)
{
    int flat = blockIdx.x * 256 + threadIdx.x;    // < 262144
    int q  = flat >> 15;                          // 0..7
    int e2 = flat & 32767;
    int s  = (P + 7) >> 3;
    int p0 = q * s;
    int p1 = p0 + s; if (p1 > P) p1 = P;
    const bf16* b = partial + (size_t)e2 * 2;
    float s0 = 0.f, s1 = 0.f;
    for (int p = p0; p < p1; ++p) {
        bf16x2 v = *reinterpret_cast<const bf16x2*>(b + (size_t)p * 65536);
        s0 += (float)v[0]; s1 += (float)v[1];
    }
    tmp[(size_t)q * 65536 + e2 * 2]     = s0;
    tmp[(size_t)q * 65536 + e2 * 2 + 1] = s1;
}

// ---------------- reduce stage 2: squash (o fully lane-local), update vsum / out ----------------
__global__ __launch_bounds__(64)
void caps_r2(const float* __restrict__ tmp, float* __restrict__ vsum,
             float* __restrict__ out, int vmode, int wout)
{
    int t = blockIdx.x * 64 + threadIdx.x;   // < 2048
    int b31  = t & 31;
    int rest = t >> 5;                        // 0..63
    int k    = rest & 31;
    int c01  = rest >> 5;
    int unit = c01 * 32 + k;

    f32x4 a[8] = {};                          // (q, hi)
#pragma unroll
    for (int p = 0; p < 8; ++p) {
        const float* tp = tmp + (size_t)p * 65536;
#pragma unroll
        for (int q = 0; q < 4; ++q) {
#pragma unroll
            for (int hh = 0; hh < 2; ++hh)
                a[q * 2 + hh] += *reinterpret_cast<const f32x4*>(
                    tp + ((size_t)unit * 4 + q) * 256 + hh * 128 + b31 * 4);
        }
    }
    float s2 = 0.f;
#pragma unroll
    for (int u = 0; u < 8; ++u)
#pragma unroll
        for (int rr = 0; rr < 4; ++rr) s2 += a[u][rr] * a[u][rr];
    float scale = s2 / (1.0f + s2) / sqrtf(s2 + 1e-7f);

    int b  = c01 * 32 + b31;
    size_t e0 = ((size_t)b * KC + k) * DOO;
#pragma unroll
    for (int q = 0; q < 4; ++q) {
#pragma unroll
        for (int hh = 0; hh < 2; ++hh) {
            int o0 = q * 8 + hh * 4;
            float4 wv;
            wv.x = scale * a[q * 2 + hh][0]; wv.y = scale * a[q * 2 + hh][1];
            wv.z = scale * a[q * 2 + hh][2]; wv.w = scale * a[q * 2 + hh][3];
            if (vmode == 0) {
                *reinterpret_cast<float4*>(vsum + e0 + o0) = wv;
            } else if (vmode == 1) {
                float4 ov = *reinterpret_cast<const float4*>(vsum + e0 + o0);
                ov.x += wv.x; ov.y += wv.y; ov.z += wv.z; ov.w += wv.w;
                *reinterpret_cast<float4*>(vsum + e0 + o0) = ov;
            }
            if (wout) *reinterpret_cast<float4*>(out + e0 + o0) = wv;
        }
    }
}

extern "C" void kernel_launch(void* const* d_in, const int* in_sizes, int n_in,
                              void* d_out, int out_size, void* d_ws, size_t ws_size,
                              hipStream_t stream)
{
    const float* X  = (const float*)d_in[0];   // [64, 2048, 16] f32
    const float* Wg = (const float*)d_in[1];   // [2048, 32, 16, 32] f32
    float* out = (float*)d_out;                // [64, 32, 32] f32

    const size_t WFRAG_B = (size_t)JJ * 32 * 64 * 8 * 2;   // 67108864
    const size_t XFRAG_B = (size_t)JJ * 2 * 64 * 8 * 2;    // 4194304
    const size_t VS_B    = 65536ull * 4;                   // 262144
    const size_t CB_B    = (size_t)BB * JJ * KC * 4;       // 16777216
    const size_t TMP_B   = 8ull * 65536 * 4;               // 2097152
    const size_t FIX_B   = VS_B + CB_B + TMP_B;

    int P = 128;
    int useFrag = 1;
    bf16 *Wfrag = nullptr, *Xfrag = nullptr, *partial = nullptr;
    float *vsum = nullptr, *cbuf = nullptr, *tmpb = nullptr;

    char* p = (char*)d_ws;
    if (ws_size >= WFRAG_B + XFRAG_B + FIX_B + (size_t)P * 65536 * 2) {
        Wfrag = (bf16*)p;            p += WFRAG_B;
        Xfrag = (bf16*)p;            p += XFRAG_B;
    } else {
        useFrag = 0;
        size_t avail = (ws_size > FIX_B) ? (ws_size - FIX_B) / (65536 * 2) : 8;
        P = (int)(avail & ~7ull);    // multiple of 8 for the XCD swizzle
        if (P < 8) P = 8;
        if (P > 128) P = 128;
    }
    vsum    = (float*)p;  p += VS_B;
    cbuf    = (float*)p;  p += CB_B;
    tmpb    = (float*)p;  p += TMP_B;
    partial = (bf16*)p;

    const int Jc = (JJ + P - 1) / P;

    if (useFrag) {
        prep_x3<<<dim3(1024), dim3(256), 0, stream>>>(X, Xfrag);

        // iter 0: fused W-prep + init (uniform c = 1/32), 2-j batched
        caps_init8<<<dim3(8 * P), dim3(512), 0, stream>>>(Xfrag, Wg, Wfrag, partial, Jc);
        caps_r1<<<dim3(1024), dim3(256), 0, stream>>>(partial, tmpb, P);
        caps_r2<<<dim3(32), dim3(64), 0, stream>>>(tmpb, vsum, out, 0, 0);

        // iter 1
        caps_logits7<<<dim3(2048), dim3(256), 0, stream>>>(Xfrag, Wfrag, vsum, cbuf);
        caps_accum2<<<dim3(8 * P), dim3(512), 0, stream>>>(Xfrag, Wfrag, cbuf, partial, Jc);
        caps_r1<<<dim3(1024), dim3(256), 0, stream>>>(partial, tmpb, P);
        caps_r2<<<dim3(32), dim3(64), 0, stream>>>(tmpb, vsum, out, 1, 0);

        // iter 2 (writes output)
        caps_logits7<<<dim3(2048), dim3(256), 0, stream>>>(Xfrag, Wfrag, vsum, cbuf);
        caps_accum2<<<dim3(8 * P), dim3(512), 0, stream>>>(Xfrag, Wfrag, cbuf, partial, Jc);
        caps_r1<<<dim3(1024), dim3(256), 0, stream>>>(partial, tmpb, P);
        caps_r2<<<dim3(32), dim3(64), 0, stream>>>(tmpb, vsum, out, 2, 1);
    } else {
        caps_mm32<0,0><<<dim3(4 * P), dim3(1024), 0, stream>>>(Xfrag, Wfrag, X, Wg, cbuf, partial, Jc);
        caps_r1<<<dim3(1024), dim3(256), 0, stream>>>(partial, tmpb, P);
        caps_r2<<<dim3(32), dim3(64), 0, stream>>>(tmpb, vsum, out, 0, 0);

        caps_logits32<0><<<dim3(1024), dim3(256), 0, stream>>>(Xfrag, Wfrag, X, Wg, vsum, cbuf);
        caps_mm32<0,1><<<dim3(4 * P), dim3(1024), 0, stream>>>(Xfrag, Wfrag, X, Wg, cbuf, partial, Jc);
        caps_r1<<<dim3(1024), dim3(256), 0, stream>>>(partial, tmpb, P);
        caps_r2<<<dim3(32), dim3(64), 0, stream>>>(tmpb, vsum, out, 1, 0);

        caps_logits32<0><<<dim3(1024), dim3(256), 0, stream>>>(Xfrag, Wfrag, X, Wg, vsum, cbuf);
        caps_mm32<0,1><<<dim3(4 * P), dim3(1024), 0, stream>>>(Xfrag, Wfrag, X, Wg, cbuf, partial, Jc);
        caps_r1<<<dim3(1024), dim3(256), 0, stream>>>(partial, tmpb, P);
        caps_r2<<<dim3(32), dim3(64), 0, stream>>>(tmpb, vsum, out, 2, 1);
    }
}

// Round 12
// 172.889 us; speedup vs baseline: 1.4974x; 1.4974x over previous
//
#include <hip/hip_runtime.h>
#include <hip/hip_bf16.h>

#define BB  64
#define JJ  2048
#define DI  16
#define KC  32
#define DOO 32
#define NKO 1024   // KC*DOO

typedef __bf16 bf16;
typedef __attribute__((ext_vector_type(8)))  __bf16 bf16x8;
typedef __attribute__((ext_vector_type(4)))  __bf16 bf16x4;
typedef __attribute__((ext_vector_type(2)))  __bf16 bf16x2;
typedef __attribute__((ext_vector_type(4)))  float  f32x4;
typedef __attribute__((ext_vector_type(16))) float  f32x16;

// ======== 32x32x16 MFMA scheme ========
// D = A(32x16) * B(16x32).  A = W-slice (rows = o), B = X (cols = b). K = i (16).
// A-frag: lane l holds row o = l&31, k i = (l>>5)*8 + e
// B-frag: lane l holds col b = l&31, k i = (l>>5)*8 + e
// C/D   : col b = lane&31, row o = (reg&3) + 8*(reg>>2) + 4*(lane>>5)   [m74/m101]

// ---------------- prep: X f32 [B][J][Di] -> B-fragment layout ----------------
__global__ __launch_bounds__(256)
void prep_x3(const float* __restrict__ X, bf16* __restrict__ Xfrag)
{
    int flat = blockIdx.x * 256 + threadIdx.x;    // < 262144
    int lane = flat & 63;
    int c01  = (flat >> 6) & 1;
    int j    = flat >> 7;
    int b    = c01 * 32 + (lane & 31);
    int i0   = (lane >> 5) * 8;
    const float* src = X + ((size_t)b * JJ + j) * DI + i0;
    bf16x8 o8;
#pragma unroll
    for (int e = 0; e < 8; ++e) o8[e] = (bf16)src[e];
    *reinterpret_cast<bf16x8*>(Xfrag + (size_t)flat * 8) = o8;
}

// XCD-aware decodes (bijective for the grids used).
__device__ __forceinline__ void decode_qjr(int id, int& q, int& jr)   // grid 4P, P%8==0
{
    q = (id >> 3) & 3; jr = ((id >> 5) << 3) | (id & 7);
}
__device__ __forceinline__ void decode_q8(int id, int& q8, int& jr)   // grid 8P, P%8==0
{
    q8 = (id >> 3) & 7; jr = ((id >> 6) << 3) | (id & 7);
}
__device__ __forceinline__ int decode_jg(int id)    // grid 1024
{
    return (id & 7) * 128 + (id >> 3);
}

// ---------------- fused prep+init, 2-j batched ----------------
__global__ __launch_bounds__(512, 6)
void caps_init8(const bf16* __restrict__ Xfrag, const float* __restrict__ Wg,
                bf16* __restrict__ Wfrag, bf16* __restrict__ partial, int Jc)
{
    const int tid  = threadIdx.x;
    const int w    = tid >> 6;
    const int lane = tid & 63;
    const int o31  = lane & 31;
    const int hi   = lane >> 5;
    int q8, jr; decode_q8(blockIdx.x, q8, jr);
    const int unit = q8 * 8 + w;
    const int k    = unit & 31;
    const int c01  = unit >> 5;

    f32x16 acc = {};

    const int j0 = jr * Jc;
    int jend = j0 + Jc; if (jend > JJ) jend = JJ;

    int j = j0;
    for (; j + 1 < jend; j += 2) {
        const float* ws0 = Wg + (size_t)j * 16384 + (size_t)k * 512 + hi * 256 + o31;
        const float* ws1 = ws0 + 16384;
        float a0[8], a1[8];
#pragma unroll
        for (int e = 0; e < 8; ++e) a0[e] = ws0[e * 32];
#pragma unroll
        for (int e = 0; e < 8; ++e) a1[e] = ws1[e * 32];
        bf16x8 fw0, fw1;
#pragma unroll
        for (int e = 0; e < 8; ++e) { fw0[e] = (bf16)a0[e]; fw1[e] = (bf16)a1[e]; }
        if (c01 == 0) {
            *reinterpret_cast<bf16x8*>(Wfrag + (((size_t)j * 32 + k) * 64 + lane) * 8)       = fw0;
            *reinterpret_cast<bf16x8*>(Wfrag + (((size_t)(j + 1) * 32 + k) * 64 + lane) * 8) = fw1;
        }
        bf16x8 fx0 = *reinterpret_cast<const bf16x8*>(Xfrag + (((size_t)j * 2 + c01) * 64 + lane) * 8);
        bf16x8 fx1 = *reinterpret_cast<const bf16x8*>(Xfrag + (((size_t)(j + 1) * 2 + c01) * 64 + lane) * 8);
        acc = __builtin_amdgcn_mfma_f32_32x32x16_bf16(fw0, fx0, acc, 0, 0, 0);
        acc = __builtin_amdgcn_mfma_f32_32x32x16_bf16(fw1, fx1, acc, 0, 0, 0);
    }
    for (; j < jend; ++j) {
        const float* ws = Wg + (size_t)j * 16384 + (size_t)k * 512 + hi * 256 + o31;
        bf16x8 fw;
#pragma unroll
        for (int e = 0; e < 8; ++e) fw[e] = (bf16)ws[e * 32];
        if (c01 == 0)
            *reinterpret_cast<bf16x8*>(Wfrag + (((size_t)j * 32 + k) * 64 + lane) * 8) = fw;
        bf16x8 fx = *reinterpret_cast<const bf16x8*>(Xfrag + (((size_t)j * 2 + c01) * 64 + lane) * 8);
        acc = __builtin_amdgcn_mfma_f32_32x32x16_bf16(fw, fx, acc, 0, 0, 0);
    }

    bf16* pout = partial + (size_t)jr * (BB * NKO);
#pragma unroll
    for (int qq = 0; qq < 4; ++qq) {
        bf16x4 o4;
#pragma unroll
        for (int rr = 0; rr < 4; ++rr) o4[rr] = (bf16)(acc[qq * 4 + rr] * 0.03125f);
        *reinterpret_cast<bf16x4*>(pout + (((size_t)unit * 4 + qq) * 64 + lane) * 4) = o4;
    }
}

// ---------------- accum, 2-deep software pipeline ----------------
__global__ __launch_bounds__(512, 6)
void caps_accum2(const bf16* __restrict__ Xfrag, const bf16* __restrict__ Wfrag,
                 const float* __restrict__ cbuf, bf16* __restrict__ partial, int Jc)
{
    const int tid  = threadIdx.x;
    const int w    = tid >> 6;
    const int lane = tid & 63;
    const int o31  = lane & 31;
    int q8, jr; decode_q8(blockIdx.x, q8, jr);
    const int unit = q8 * 8 + w;
    const int k    = unit & 31;
    const int c01  = unit >> 5;
    const int b    = c01 * 32 + o31;

    const f32x16 ZV16 = {};
    f32x16 acc = ZV16;

    const int j0 = jr * Jc;
    int jend = j0 + Jc; if (jend > JJ) jend = JJ;

    auto ldx = [&](int j) {
        return *reinterpret_cast<const bf16x8*>(Xfrag + (((size_t)j * 2 + c01) * 64 + lane) * 8);
    };
    auto ldw = [&](int j) {
        return *reinterpret_cast<const bf16x8*>(Wfrag + (((size_t)j * 32 + k) * 64 + lane) * 8);
    };
    auto ldc = [&](int j) {
        return cbuf[((size_t)j * 32 + k) * 64 + b];
    };

    bf16x8 fx = ldx(j0), fw = ldw(j0);
    float  cw = ldc(j0);

    for (int j = j0; j < jend; ++j) {
        const int jn = (j + 1 < jend) ? j + 1 : j;
        bf16x8 nfx = ldx(jn);
        bf16x8 nfw = ldw(jn);
        float  ncw = ldc(jn);
        f32x16 h = __builtin_amdgcn_mfma_f32_32x32x16_bf16(fw, fx, ZV16, 0, 0, 0);
#pragma unroll
        for (int r = 0; r < 16; ++r) acc[r] += cw * h[r];
        fx = nfx; fw = nfw; cw = ncw;
    }

    bf16* pout = partial + (size_t)jr * (BB * NKO);
#pragma unroll
    for (int qq = 0; qq < 4; ++qq) {
        bf16x4 o4;
#pragma unroll
        for (int rr = 0; rr < 4; ++rr) o4[rr] = (bf16)(acc[qq * 4 + rr]);
        *reinterpret_cast<bf16x4*>(pout + (((size_t)unit * 4 + qq) * 64 + lane) * 4) = o4;
    }
}

// ---------------- logits: coalesced vsumT reads, 2-j batch, lane-local softmax ----------------
// Block 512 = 8 waves = (c01, kh2): kh2 owns 8 k's. Grid 1024 (2 j per block).
// vsumT[k][o][b]: for fixed (k,o), lanes read consecutive b -> every v-load coalesced.
__global__ __launch_bounds__(512, 6)
void caps_logits8(const bf16* __restrict__ Xfrag, const bf16* __restrict__ Wfrag,
                  const float* __restrict__ vsumT, float* __restrict__ cbuf)
{
    __shared__ float lex[2][2][32][32];   // [c01][jj][k][b31] = 16 KB

    const int tid  = threadIdx.x;
    const int wv   = tid >> 6;
    const int lane = tid & 63;
    const int b31  = lane & 31;
    const int hi   = lane >> 5;
    const int c01  = wv & 1;
    const int kh2  = wv >> 1;            // 0..3
    const int jg   = decode_jg(blockIdx.x);
    const int j0   = jg * 2;
    const int b    = c01 * 32 + b31;

    const f32x16 ZV16 = {};

    bf16x8 fx0 = *reinterpret_cast<const bf16x8*>(Xfrag + (((size_t)j0 * 2 + c01) * 64 + lane) * 8);
    bf16x8 fx1 = *reinterpret_cast<const bf16x8*>(Xfrag + (((size_t)(j0 + 1) * 2 + c01) * 64 + lane) * 8);

    float lk[2][8];
#pragma unroll
    for (int kk = 0; kk < 8; ++kk) {
        const int k = kh2 * 8 + kk;
        // coalesced v loads: v[reg] for o = (reg&3) + 8*(reg>>2) + 4*hi
        const float* vt = vsumT + (size_t)k * 2048 + hi * 256 + b;
        float v[16];
#pragma unroll
        for (int qq = 0; qq < 4; ++qq)
#pragma unroll
            for (int rr = 0; rr < 4; ++rr)
                v[qq * 4 + rr] = vt[qq * 512 + rr * 64];
        const bf16* wf = Wfrag + (((size_t)j0 * 32 + k) * 64 + lane) * 8;
        bf16x8 fwa = *reinterpret_cast<const bf16x8*>(wf);
        bf16x8 fwb = *reinterpret_cast<const bf16x8*>(wf + 16384);
        f32x16 h0 = __builtin_amdgcn_mfma_f32_32x32x16_bf16(fwa, fx0, ZV16, 0, 0, 0);
        float a0 = 0.f;
#pragma unroll
        for (int r = 0; r < 16; ++r) a0 += h0[r] * v[r];
        f32x16 h1 = __builtin_amdgcn_mfma_f32_32x32x16_bf16(fwb, fx1, ZV16, 0, 0, 0);
        float a1 = 0.f;
#pragma unroll
        for (int r = 0; r < 16; ++r) a1 += h1[r] * v[r];
        a0 += __shfl_xor(a0, 32, 64);
        a1 += __shfl_xor(a1, 32, 64);
        lk[0][kk] = a0; lk[1][kk] = a1;
    }

    if (hi == 0) {
#pragma unroll
        for (int jj = 0; jj < 2; ++jj)
#pragma unroll
            for (int kk = 0; kk < 8; ++kk)
                lex[c01][jj][kh2 * 8 + kk][b31] = lk[jj][kk];
    }
    __syncthreads();

    // softmax over full K=32 per (c01, jj, b31); incremental over LDS (no big array)
#pragma unroll
    for (int jj = 0; jj < 2; ++jj) {
        float mx = lex[c01][jj][0][b31];
#pragma unroll
        for (int k = 1; k < 32; ++k) mx = fmaxf(mx, lex[c01][jj][k][b31]);
        float sm = 0.f;
#pragma unroll
        for (int k = 0; k < 32; ++k) sm += __expf(lex[c01][jj][k][b31] - mx);
        float inv = 1.0f / sm;
#pragma unroll
        for (int kk = 0; kk < 8; ++kk)
            lk[jj][kk] = __expf(lk[jj][kk] - mx) * inv;
    }
    __syncthreads();   // all raw reads done before overwrite

    if (hi == 0) {
#pragma unroll
        for (int jj = 0; jj < 2; ++jj)
#pragma unroll
            for (int kk = 0; kk < 8; ++kk)
                lex[c01][jj][kh2 * 8 + kk][b31] = lk[jj][kk];
    }
    __syncthreads();

    // coalesced c write: cbuf[j][k][b]
    float* cj = cbuf + (size_t)j0 * 2048;
#pragma unroll
    for (int it = 0; it < 8; ++it) {
        int idx = it * 512 + tid;            // < 4096
        int b64 = idx & 63;
        int k   = (idx >> 6) & 31;
        int j2  = idx >> 11;
        cj[(size_t)j2 * 2048 + k * 64 + b64] = lex[b64 >> 5][j2][k][b64 & 31];
    }
}

// ---------------- fallback kernels (raw f32 path) ----------------
template<int UF, int MODE>
__global__ __launch_bounds__(1024, 8)
void caps_mm32(const bf16* __restrict__ Xfrag, const bf16* __restrict__ Wfrag,
               const float* __restrict__ Xf, const float* __restrict__ Wf,
               const float* __restrict__ cbuf, bf16* __restrict__ partial, int Jc)
{
    const int tid  = threadIdx.x;
    const int w    = tid >> 6;
    const int lane = tid & 63;
    const int o31  = lane & 31;
    const int hi   = lane >> 5;
    int q, jr; decode_qjr(blockIdx.x, q, jr);
    const int unit = q * 16 + w;
    const int k    = unit & 31;
    const int c01  = unit >> 5;
    const int b    = c01 * 32 + o31;

    const f32x16 ZV16 = {};
    f32x16 acc = ZV16;

    const int j0 = jr * Jc;
    int jend = j0 + Jc; if (jend > JJ) jend = JJ;

    for (int j = j0; j < jend; ++j) {
        bf16x8 fx, fw;
        if constexpr (UF) {
            fx = *reinterpret_cast<const bf16x8*>(Xfrag + (((size_t)j * 2 + c01) * 64 + lane) * 8);
            fw = *reinterpret_cast<const bf16x8*>(Wfrag + (((size_t)j * 32 + k) * 64 + lane) * 8);
        } else {
            const float* xs = Xf + ((size_t)b * JJ + j) * DI + hi * 8;
#pragma unroll
            for (int e = 0; e < 8; ++e) fx[e] = (bf16)xs[e];
            const float* ws = Wf + (size_t)j * 16384 + (size_t)k * 512 + hi * 256 + o31;
#pragma unroll
            for (int e = 0; e < 8; ++e) fw[e] = (bf16)ws[e * 32];
        }
        if constexpr (MODE == 0) {
            acc = __builtin_amdgcn_mfma_f32_32x32x16_bf16(fw, fx, acc, 0, 0, 0);
        } else {
            float cw = cbuf[((size_t)j * 32 + k) * 64 + b];
            f32x16 h = __builtin_amdgcn_mfma_f32_32x32x16_bf16(fw, fx, ZV16, 0, 0, 0);
#pragma unroll
            for (int r = 0; r < 16; ++r) acc[r] += cw * h[r];
        }
    }

    const float esc = (MODE == 0) ? 0.03125f : 1.0f;
    bf16* pout = partial + (size_t)jr * (BB * NKO);
#pragma unroll
    for (int qq = 0; qq < 4; ++qq) {
        bf16x4 o4;
#pragma unroll
        for (int rr = 0; rr < 4; ++rr) o4[rr] = (bf16)(acc[qq * 4 + rr] * esc);
        *reinterpret_cast<bf16x4*>(pout + (((size_t)unit * 4 + qq) * 64 + lane) * 4) = o4;
    }
}

template<int UF>
__global__ __launch_bounds__(256, 6)
void caps_logits32(const bf16* __restrict__ Xfrag, const bf16* __restrict__ Wfrag,
                   const float* __restrict__ Xf, const float* __restrict__ Wf,
                   const float* __restrict__ vsum, float* __restrict__ cbuf)
{
    __shared__ float cl[2][64][33];

    const int tid  = threadIdx.x;
    const int w    = tid >> 6;
    const int lane = tid & 63;
    const int o31  = lane & 31;
    const int hi   = lane >> 5;
    const int jg   = decode_jg(blockIdx.x);
    const int j0   = jg * 2;
    const int jj   = w >> 1;
    const int c01  = w & 1;
    const int j    = j0 + jj;
    const int b    = c01 * 32 + o31;

    const f32x16 ZV16 = {};

    bf16x8 fx;
    if constexpr (UF) {
        fx = *reinterpret_cast<const bf16x8*>(Xfrag + (((size_t)j * 2 + c01) * 64 + lane) * 8);
    } else {
        const float* xs = Xf + ((size_t)b * JJ + j) * DI + hi * 8;
#pragma unroll
        for (int e = 0; e < 8; ++e) fx[e] = (bf16)xs[e];
    }

    const float* vb = vsum + (size_t)b * NKO + hi * 4;
    float lk[32];
#pragma unroll
    for (int k = 0; k < 32; ++k) {
        bf16x8 fw;
        if constexpr (UF) {
            fw = *reinterpret_cast<const bf16x8*>(Wfrag + (((size_t)j * 32 + k) * 64 + lane) * 8);
        } else {
            const float* ws = Wf + (size_t)j * 16384 + (size_t)k * 512 + hi * 256 + o31;
#pragma unroll
            for (int e = 0; e < 8; ++e) fw[e] = (bf16)ws[e * 32];
        }
        f32x16 h = __builtin_amdgcn_mfma_f32_32x32x16_bf16(fw, fx, ZV16, 0, 0, 0);
        float a = 0.f;
        const float* vk = vb + k * 32;
#pragma unroll
        for (int qq = 0; qq < 4; ++qq) {
            float4 v4 = *reinterpret_cast<const float4*>(vk + qq * 8);
            a += h[qq * 4 + 0] * v4.x + h[qq * 4 + 1] * v4.y
               + h[qq * 4 + 2] * v4.z + h[qq * 4 + 3] * v4.w;
        }
        a += __shfl_xor(a, 32, 64);
        lk[k] = a;
    }

    float mx = lk[0];
#pragma unroll
    for (int k = 1; k < 32; ++k) mx = fmaxf(mx, lk[k]);
    float sm = 0.f;
#pragma unroll
    for (int k = 0; k < 32; ++k) { lk[k] = __expf(lk[k] - mx); sm += lk[k]; }
    float inv = 1.0f / sm;

    if (hi == 0) {
#pragma unroll
        for (int k = 0; k < 32; ++k) cl[jj][b][k] = lk[k] * inv;
    }
    __syncthreads();

#pragma unroll
    for (int j2 = 0; j2 < 2; ++j2) {
#pragma unroll
        for (int i = 0; i < 8; ++i) {
            int idx = i * 256 + tid;
            int kk = idx >> 6, bb = idx & 63;
            cbuf[((size_t)(j0 + j2) * 32 + kk) * 64 + bb] = cl[j2][bb][kk];
        }
    }
}

// ---------------- reduce stage 1: sum P slices in 8 groups -> tmp f32 [8][65536] ----------------
__global__ __launch_bounds__(256)
void caps_r1(const bf16* __restrict__ partial, float* __restrict__ tmp, int P)
{
    int flat = blockIdx.x * 256 + threadIdx.x;    // < 262144
    int q  = flat >> 15;                          // 0..7
    int e2 = flat & 32767;
    int s  = (P + 7) >> 3;
    int p0 = q * s;
    int p1 = p0 + s; if (p1 > P) p1 = P;
    const bf16* b = partial + (size_t)e2 * 2;
    float s0 = 0.f, s1 = 0.f;
    for (int p = p0; p < p1; ++p) {
        bf16x2 v = *reinterpret_cast<const bf16x2*>(b + (size_t)p * 65536);
        s0 += (float)v[0]; s1 += (float)v[1];
    }
    tmp[(size_t)q * 65536 + e2 * 2]     = s0;
    tmp[(size_t)q * 65536 + e2 * 2 + 1] = s1;
}

// ---------------- reduce stage 2: squash; update vsum (std) + vsumT (transposed) ----------------
__global__ __launch_bounds__(64)
void caps_r2(const float* __restrict__ tmp, float* __restrict__ vsum, float* __restrict__ vsumT,
             float* __restrict__ out, int vmode, int wout)
{
    int t = blockIdx.x * 64 + threadIdx.x;   // < 2048
    int b31  = t & 31;
    int rest = t >> 5;
    int k    = rest & 31;
    int c01  = rest >> 5;
    int unit = c01 * 32 + k;

    f32x4 a[8] = {};                          // (q, hi)
#pragma unroll
    for (int p = 0; p < 8; ++p) {
        const float* tp = tmp + (size_t)p * 65536;
#pragma unroll
        for (int q = 0; q < 4; ++q) {
#pragma unroll
            for (int hh = 0; hh < 2; ++hh)
                a[q * 2 + hh] += *reinterpret_cast<const f32x4*>(
                    tp + ((size_t)unit * 4 + q) * 256 + hh * 128 + b31 * 4);
        }
    }
    float s2 = 0.f;
#pragma unroll
    for (int u = 0; u < 8; ++u)
#pragma unroll
        for (int rr = 0; rr < 4; ++rr) s2 += a[u][rr] * a[u][rr];
    float scale = s2 / (1.0f + s2) / sqrtf(s2 + 1e-7f);

    int b  = c01 * 32 + b31;
    size_t e0 = ((size_t)b * KC + k) * DOO;
#pragma unroll
    for (int q = 0; q < 4; ++q) {
#pragma unroll
        for (int hh = 0; hh < 2; ++hh) {
            int u  = q * 2 + hh;
            int o0 = q * 8 + hh * 4;
            float4 wv, nv;
            wv.x = scale * a[u][0]; wv.y = scale * a[u][1];
            wv.z = scale * a[u][2]; wv.w = scale * a[u][3];
            if (vmode == 0) {
                nv = wv;
            } else if (vmode == 1) {
                float4 ov = *reinterpret_cast<const float4*>(vsum + e0 + o0);
                nv.x = ov.x + wv.x; nv.y = ov.y + wv.y;
                nv.z = ov.z + wv.z; nv.w = ov.w + wv.w;
            }
            if (vmode < 2) {
                *reinterpret_cast<float4*>(vsum + e0 + o0) = nv;
                vsumT[((size_t)k * 32 + o0 + 0) * 64 + b] = nv.x;
                vsumT[((size_t)k * 32 + o0 + 1) * 64 + b] = nv.y;
                vsumT[((size_t)k * 32 + o0 + 2) * 64 + b] = nv.z;
                vsumT[((size_t)k * 32 + o0 + 3) * 64 + b] = nv.w;
            }
            if (wout) *reinterpret_cast<float4*>(out + e0 + o0) = wv;
        }
    }
}

extern "C" void kernel_launch(void* const* d_in, const int* in_sizes, int n_in,
                              void* d_out, int out_size, void* d_ws, size_t ws_size,
                              hipStream_t stream)
{
    const float* X  = (const float*)d_in[0];   // [64, 2048, 16] f32
    const float* Wg = (const float*)d_in[1];   // [2048, 32, 16, 32] f32
    float* out = (float*)d_out;                // [64, 32, 32] f32

    const size_t WFRAG_B = (size_t)JJ * 32 * 64 * 8 * 2;   // 67108864
    const size_t XFRAG_B = (size_t)JJ * 2 * 64 * 8 * 2;    // 4194304
    const size_t VS_B    = 65536ull * 4;                   // 262144
    const size_t VT_B    = 65536ull * 4;                   // 262144 (transposed copy)
    const size_t CB_B    = (size_t)BB * JJ * KC * 4;       // 16777216
    const size_t TMP_B   = 8ull * 65536 * 4;               // 2097152
    const size_t FIX_B   = VS_B + VT_B + CB_B + TMP_B;

    int P = 128;
    int useFrag = 1;
    bf16 *Wfrag = nullptr, *Xfrag = nullptr, *partial = nullptr;
    float *vsum = nullptr, *vsumT = nullptr, *cbuf = nullptr, *tmpb = nullptr;

    char* p = (char*)d_ws;
    if (ws_size >= WFRAG_B + XFRAG_B + FIX_B + (size_t)P * 65536 * 2) {
        Wfrag = (bf16*)p;            p += WFRAG_B;
        Xfrag = (bf16*)p;            p += XFRAG_B;
    } else {
        useFrag = 0;
        size_t avail = (ws_size > FIX_B) ? (ws_size - FIX_B) / (65536 * 2) : 8;
        P = (int)(avail & ~7ull);    // multiple of 8 for the XCD swizzle
        if (P < 8) P = 8;
        if (P > 128) P = 128;
    }
    vsum    = (float*)p;  p += VS_B;
    vsumT   = (float*)p;  p += VT_B;
    cbuf    = (float*)p;  p += CB_B;
    tmpb    = (float*)p;  p += TMP_B;
    partial = (bf16*)p;

    const int Jc = (JJ + P - 1) / P;

    if (useFrag) {
        prep_x3<<<dim3(1024), dim3(256), 0, stream>>>(X, Xfrag);

        // iter 0: fused W-prep + init (uniform c = 1/32)
        caps_init8<<<dim3(8 * P), dim3(512), 0, stream>>>(Xfrag, Wg, Wfrag, partial, Jc);
        caps_r1<<<dim3(1024), dim3(256), 0, stream>>>(partial, tmpb, P);
        caps_r2<<<dim3(32), dim3(64), 0, stream>>>(tmpb, vsum, vsumT, out, 0, 0);

        // iter 1
        caps_logits8<<<dim3(1024), dim3(512), 0, stream>>>(Xfrag, Wfrag, vsumT, cbuf);
        caps_accum2<<<dim3(8 * P), dim3(512), 0, stream>>>(Xfrag, Wfrag, cbuf, partial, Jc);
        caps_r1<<<dim3(1024), dim3(256), 0, stream>>>(partial, tmpb, P);
        caps_r2<<<dim3(32), dim3(64), 0, stream>>>(tmpb, vsum, vsumT, out, 1, 0);

        // iter 2 (writes output)
        caps_logits8<<<dim3(1024), dim3(512), 0, stream>>>(Xfrag, Wfrag, vsumT, cbuf);
        caps_accum2<<<dim3(8 * P), dim3(512), 0, stream>>>(Xfrag, Wfrag, cbuf, partial, Jc);
        caps_r1<<<dim3(1024), dim3(256), 0, stream>>>(partial, tmpb, P);
        caps_r2<<<dim3(32), dim3(64), 0, stream>>>(tmpb, vsum, vsumT, out, 2, 1);
    } else {
        caps_mm32<0,0><<<dim3(4 * P), dim3(1024), 0, stream>>>(Xfrag, Wfrag, X, Wg, cbuf, partial, Jc);
        caps_r1<<<dim3(1024), dim3(256), 0, stream>>>(partial, tmpb, P);
        caps_r2<<<dim3(32), dim3(64), 0, stream>>>(tmpb, vsum, vsumT, out, 0, 0);

        caps_logits32<0><<<dim3(1024), dim3(256), 0, stream>>>(Xfrag, Wfrag, X, Wg, vsum, cbuf);
        caps_mm32<0,1><<<dim3(4 * P), dim3(1024), 0, stream>>>(Xfrag, Wfrag, X, Wg, cbuf, partial, Jc);
        caps_r1<<<dim3(1024), dim3(256), 0, stream>>>(partial, tmpb, P);
        caps_r2<<<dim3(32), dim3(64), 0, stream>>>(tmpb, vsum, vsumT, out, 1, 0);

        caps_logits32<0><<<dim3(1024), dim3(256), 0, stream>>>(Xfrag, Wfrag, X, Wg, vsum, cbuf);
        caps_mm32<0,1><<<dim3(4 * P), dim3(1024), 0, stream>>>(Xfrag, Wfrag, X, Wg, cbuf, partial, Jc);
        caps_r1<<<dim3(1024), dim3(256), 0, stream>>>(partial, tmpb, P);
        caps_r2<<<dim3(32), dim3(64), 0, stream>>>(tmpb, vsum, vsumT, out, 2, 1);
    }
}

// Round 13
// 161.967 us; speedup vs baseline: 1.5983x; 1.0674x over previous
//
#include <hip/hip_runtime.h>
#include <hip/hip_bf16.h>

#define BB  64
#define JJ  2048
#define DI  16
#define KC  32
#define DOO 32
#define NKO 1024   // KC*DOO

typedef __bf16 bf16;
typedef __attribute__((ext_vector_type(8)))  __bf16 bf16x8;
typedef __attribute__((ext_vector_type(4)))  __bf16 bf16x4;
typedef __attribute__((ext_vector_type(4)))  float  f32x4;
typedef __attribute__((ext_vector_type(16))) float  f32x16;

// ======== 32x32x16 MFMA scheme ========
// D = A(32x16) * B(16x32).  A = W-slice (rows = o), B = X (cols = b). K = i (16).
// A-frag: lane l holds row o = l&31, k i = (l>>5)*8 + e
// B-frag: lane l holds col b = l&31, k i = (l>>5)*8 + e
// C/D   : col b = lane&31, row o = (reg&3) + 8*(reg>>2) + 4*(lane>>5)   [m74/m101]

// ---------------- prep: X f32 [B][J][Di] -> B-fragment layout ----------------
__global__ __launch_bounds__(256)
void prep_x3(const float* __restrict__ X, bf16* __restrict__ Xfrag)
{
    int flat = blockIdx.x * 256 + threadIdx.x;    // < 262144
    int lane = flat & 63;
    int c01  = (flat >> 6) & 1;
    int j    = flat >> 7;
    int b    = c01 * 32 + (lane & 31);
    int i0   = (lane >> 5) * 8;
    const float* src = X + ((size_t)b * JJ + j) * DI + i0;
    bf16x8 o8;
#pragma unroll
    for (int e = 0; e < 8; ++e) o8[e] = (bf16)src[e];
    *reinterpret_cast<bf16x8*>(Xfrag + (size_t)flat * 8) = o8;
}

// XCD-aware decodes (bijective for the grids used).
__device__ __forceinline__ void decode_qjr(int id, int& q, int& jr)   // grid 4P, P%8==0
{
    q = (id >> 3) & 3; jr = ((id >> 5) << 3) | (id & 7);
}
__device__ __forceinline__ void decode_q8(int id, int& q8, int& jr)   // grid 8P, P%8==0
{
    q8 = (id >> 3) & 7; jr = ((id >> 6) << 3) | (id & 7);
}
__device__ __forceinline__ int decode_jg(int id)    // grid 1024
{
    return (id & 7) * 128 + (id >> 3);
}

// ---------------- fused prep+init, 2-j batched ----------------
__global__ __launch_bounds__(512, 6)
void caps_init8(const bf16* __restrict__ Xfrag, const float* __restrict__ Wg,
                bf16* __restrict__ Wfrag, bf16* __restrict__ partial, int Jc)
{
    const int tid  = threadIdx.x;
    const int w    = tid >> 6;
    const int lane = tid & 63;
    const int o31  = lane & 31;
    const int hi   = lane >> 5;
    int q8, jr; decode_q8(blockIdx.x, q8, jr);
    const int unit = q8 * 8 + w;
    const int k    = unit & 31;
    const int c01  = unit >> 5;

    f32x16 acc = {};

    const int j0 = jr * Jc;
    int jend = j0 + Jc; if (jend > JJ) jend = JJ;

    int j = j0;
    for (; j + 1 < jend; j += 2) {
        const float* ws0 = Wg + (size_t)j * 16384 + (size_t)k * 512 + hi * 256 + o31;
        const float* ws1 = ws0 + 16384;
        float a0[8], a1[8];
#pragma unroll
        for (int e = 0; e < 8; ++e) a0[e] = ws0[e * 32];
#pragma unroll
        for (int e = 0; e < 8; ++e) a1[e] = ws1[e * 32];
        bf16x8 fw0, fw1;
#pragma unroll
        for (int e = 0; e < 8; ++e) { fw0[e] = (bf16)a0[e]; fw1[e] = (bf16)a1[e]; }
        if (c01 == 0) {
            *reinterpret_cast<bf16x8*>(Wfrag + (((size_t)j * 32 + k) * 64 + lane) * 8)       = fw0;
            *reinterpret_cast<bf16x8*>(Wfrag + (((size_t)(j + 1) * 32 + k) * 64 + lane) * 8) = fw1;
        }
        bf16x8 fx0 = *reinterpret_cast<const bf16x8*>(Xfrag + (((size_t)j * 2 + c01) * 64 + lane) * 8);
        bf16x8 fx1 = *reinterpret_cast<const bf16x8*>(Xfrag + (((size_t)(j + 1) * 2 + c01) * 64 + lane) * 8);
        acc = __builtin_amdgcn_mfma_f32_32x32x16_bf16(fw0, fx0, acc, 0, 0, 0);
        acc = __builtin_amdgcn_mfma_f32_32x32x16_bf16(fw1, fx1, acc, 0, 0, 0);
    }
    for (; j < jend; ++j) {
        const float* ws = Wg + (size_t)j * 16384 + (size_t)k * 512 + hi * 256 + o31;
        bf16x8 fw;
#pragma unroll
        for (int e = 0; e < 8; ++e) fw[e] = (bf16)ws[e * 32];
        if (c01 == 0)
            *reinterpret_cast<bf16x8*>(Wfrag + (((size_t)j * 32 + k) * 64 + lane) * 8) = fw;
        bf16x8 fx = *reinterpret_cast<const bf16x8*>(Xfrag + (((size_t)j * 2 + c01) * 64 + lane) * 8);
        acc = __builtin_amdgcn_mfma_f32_32x32x16_bf16(fw, fx, acc, 0, 0, 0);
    }

    bf16* pout = partial + (size_t)jr * (BB * NKO);
#pragma unroll
    for (int qq = 0; qq < 4; ++qq) {
        bf16x4 o4;
#pragma unroll
        for (int rr = 0; rr < 4; ++rr) o4[rr] = (bf16)(acc[qq * 4 + rr] * 0.03125f);
        *reinterpret_cast<bf16x4*>(pout + (((size_t)unit * 4 + qq) * 64 + lane) * 4) = o4;
    }
}

// ---------------- accum, 2-deep software pipeline ----------------
__global__ __launch_bounds__(512, 6)
void caps_accum2(const bf16* __restrict__ Xfrag, const bf16* __restrict__ Wfrag,
                 const float* __restrict__ cbuf, bf16* __restrict__ partial, int Jc)
{
    const int tid  = threadIdx.x;
    const int w    = tid >> 6;
    const int lane = tid & 63;
    const int o31  = lane & 31;
    int q8, jr; decode_q8(blockIdx.x, q8, jr);
    const int unit = q8 * 8 + w;
    const int k    = unit & 31;
    const int c01  = unit >> 5;
    const int b    = c01 * 32 + o31;

    const f32x16 ZV16 = {};
    f32x16 acc = ZV16;

    const int j0 = jr * Jc;
    int jend = j0 + Jc; if (jend > JJ) jend = JJ;

    auto ldx = [&](int j) {
        return *reinterpret_cast<const bf16x8*>(Xfrag + (((size_t)j * 2 + c01) * 64 + lane) * 8);
    };
    auto ldw = [&](int j) {
        return *reinterpret_cast<const bf16x8*>(Wfrag + (((size_t)j * 32 + k) * 64 + lane) * 8);
    };
    auto ldc = [&](int j) {
        return cbuf[((size_t)j * 32 + k) * 64 + b];
    };

    bf16x8 fx = ldx(j0), fw = ldw(j0);
    float  cw = ldc(j0);

    for (int j = j0; j < jend; ++j) {
        const int jn = (j + 1 < jend) ? j + 1 : j;
        bf16x8 nfx = ldx(jn);
        bf16x8 nfw = ldw(jn);
        float  ncw = ldc(jn);
        f32x16 h = __builtin_amdgcn_mfma_f32_32x32x16_bf16(fw, fx, ZV16, 0, 0, 0);
#pragma unroll
        for (int r = 0; r < 16; ++r) acc[r] += cw * h[r];
        fx = nfx; fw = nfw; cw = ncw;
    }

    bf16* pout = partial + (size_t)jr * (BB * NKO);
#pragma unroll
    for (int qq = 0; qq < 4; ++qq) {
        bf16x4 o4;
#pragma unroll
        for (int rr = 0; rr < 4; ++rr) o4[rr] = (bf16)(acc[qq * 4 + rr]);
        *reinterpret_cast<bf16x4*>(pout + (((size_t)unit * 4 + qq) * 64 + lane) * 4) = o4;
    }
}

// ---------------- logits: coalesced vsumT reads, 2-j batch, lane-local softmax ----------------
__global__ __launch_bounds__(512, 6)
void caps_logits8(const bf16* __restrict__ Xfrag, const bf16* __restrict__ Wfrag,
                  const float* __restrict__ vsumT, float* __restrict__ cbuf)
{
    __shared__ float lex[2][2][32][32];   // [c01][jj][k][b31] = 16 KB

    const int tid  = threadIdx.x;
    const int wv   = tid >> 6;
    const int lane = tid & 63;
    const int b31  = lane & 31;
    const int hi   = lane >> 5;
    const int c01  = wv & 1;
    const int kh2  = wv >> 1;            // 0..3
    const int jg   = decode_jg(blockIdx.x);
    const int j0   = jg * 2;
    const int b    = c01 * 32 + b31;

    const f32x16 ZV16 = {};

    bf16x8 fx0 = *reinterpret_cast<const bf16x8*>(Xfrag + (((size_t)j0 * 2 + c01) * 64 + lane) * 8);
    bf16x8 fx1 = *reinterpret_cast<const bf16x8*>(Xfrag + (((size_t)(j0 + 1) * 2 + c01) * 64 + lane) * 8);

    float lk[2][8];
#pragma unroll
    for (int kk = 0; kk < 8; ++kk) {
        const int k = kh2 * 8 + kk;
        const float* vt = vsumT + (size_t)k * 2048 + hi * 256 + b;
        float v[16];
#pragma unroll
        for (int qq = 0; qq < 4; ++qq)
#pragma unroll
            for (int rr = 0; rr < 4; ++rr)
                v[qq * 4 + rr] = vt[qq * 512 + rr * 64];
        const bf16* wf = Wfrag + (((size_t)j0 * 32 + k) * 64 + lane) * 8;
        bf16x8 fwa = *reinterpret_cast<const bf16x8*>(wf);
        bf16x8 fwb = *reinterpret_cast<const bf16x8*>(wf + 16384);
        f32x16 h0 = __builtin_amdgcn_mfma_f32_32x32x16_bf16(fwa, fx0, ZV16, 0, 0, 0);
        float a0 = 0.f;
#pragma unroll
        for (int r = 0; r < 16; ++r) a0 += h0[r] * v[r];
        f32x16 h1 = __builtin_amdgcn_mfma_f32_32x32x16_bf16(fwb, fx1, ZV16, 0, 0, 0);
        float a1 = 0.f;
#pragma unroll
        for (int r = 0; r < 16; ++r) a1 += h1[r] * v[r];
        a0 += __shfl_xor(a0, 32, 64);
        a1 += __shfl_xor(a1, 32, 64);
        lk[0][kk] = a0; lk[1][kk] = a1;
    }

    if (hi == 0) {
#pragma unroll
        for (int jj = 0; jj < 2; ++jj)
#pragma unroll
            for (int kk = 0; kk < 8; ++kk)
                lex[c01][jj][kh2 * 8 + kk][b31] = lk[jj][kk];
    }
    __syncthreads();

#pragma unroll
    for (int jj = 0; jj < 2; ++jj) {
        float mx = lex[c01][jj][0][b31];
#pragma unroll
        for (int k = 1; k < 32; ++k) mx = fmaxf(mx, lex[c01][jj][k][b31]);
        float sm = 0.f;
#pragma unroll
        for (int k = 0; k < 32; ++k) sm += __expf(lex[c01][jj][k][b31] - mx);
        float inv = 1.0f / sm;
#pragma unroll
        for (int kk = 0; kk < 8; ++kk)
            lk[jj][kk] = __expf(lk[jj][kk] - mx) * inv;
    }
    __syncthreads();

    if (hi == 0) {
#pragma unroll
        for (int jj = 0; jj < 2; ++jj)
#pragma unroll
            for (int kk = 0; kk < 8; ++kk)
                lex[c01][jj][kh2 * 8 + kk][b31] = lk[jj][kk];
    }
    __syncthreads();

    float* cj = cbuf + (size_t)j0 * 2048;
#pragma unroll
    for (int it = 0; it < 8; ++it) {
        int idx = it * 512 + tid;            // < 4096
        int b64 = idx & 63;
        int k   = (idx >> 6) & 31;
        int j2  = idx >> 11;
        cj[(size_t)j2 * 2048 + k * 64 + b64] = lex[b64 >> 5][j2][k][b64 & 31];
    }
}

// ---------------- merged reduce: sum P slices + squash + update vsum/vsumT/out ----------------
// Grid 64 blocks (one per unit = c01*32 + k), 256 threads: tid = qq*64 + hi*32 + b31.
// Thread sums its bf16x4 group (b = c01*32+b31, o = rr + 8qq + 4hi) over all P slices,
// squash via shfl_xor(32) (hi fold) + 4x32 LDS fold (qq), then writes directly.
__global__ __launch_bounds__(256)
void caps_red(const bf16* __restrict__ partial, float* __restrict__ vsum, float* __restrict__ vsumT,
              float* __restrict__ out, int P, int vmode, int wout)
{
    __shared__ float lds[4][32];
    const int unit = blockIdx.x;          // 0..63
    const int tid  = threadIdx.x;
    const int b31  = tid & 31;
    const int hi   = (tid >> 5) & 1;
    const int qq   = tid >> 6;
    const int k    = unit & 31;
    const int c01  = unit >> 5;

    const bf16* base = partial + (size_t)unit * 1024 + (size_t)tid * 4;
    f32x4 a = {};
    int p = 0;
    for (; p + 8 <= P; p += 8) {
        bf16x4 v[8];
#pragma unroll
        for (int u = 0; u < 8; ++u)
            v[u] = *reinterpret_cast<const bf16x4*>(base + (size_t)(p + u) * 65536);
#pragma unroll
        for (int u = 0; u < 8; ++u)
#pragma unroll
            for (int rr = 0; rr < 4; ++rr) a[rr] += (float)v[u][rr];
    }
    for (; p < P; ++p) {
        bf16x4 v = *reinterpret_cast<const bf16x4*>(base + (size_t)p * 65536);
#pragma unroll
        for (int rr = 0; rr < 4; ++rr) a[rr] += (float)v[rr];
    }

    float s2l = a[0] * a[0] + a[1] * a[1] + a[2] * a[2] + a[3] * a[3];
    s2l += __shfl_xor(s2l, 32, 64);           // fold hi (lanes b31 <-> 32+b31)
    if ((tid & 63) < 32) lds[qq][b31] = s2l;  // wave index == qq
    __syncthreads();
    float s2 = lds[0][b31] + lds[1][b31] + lds[2][b31] + lds[3][b31];
    float scale = s2 / (1.0f + s2) / sqrtf(s2 + 1e-7f);

    const int b  = c01 * 32 + b31;
    const int o0 = qq * 8 + hi * 4;
    size_t e0 = ((size_t)b * KC + k) * DOO + o0;
    float4 wv, nv;
    wv.x = scale * a[0]; wv.y = scale * a[1]; wv.z = scale * a[2]; wv.w = scale * a[3];
    if (vmode == 0) {
        nv = wv;
    } else if (vmode == 1) {
        float4 ov = *reinterpret_cast<const float4*>(vsum + e0);
        nv.x = ov.x + wv.x; nv.y = ov.y + wv.y; nv.z = ov.z + wv.z; nv.w = ov.w + wv.w;
    }
    if (vmode < 2) {
        *reinterpret_cast<float4*>(vsum + e0) = nv;
        vsumT[((size_t)k * 32 + o0 + 0) * 64 + b] = nv.x;
        vsumT[((size_t)k * 32 + o0 + 1) * 64 + b] = nv.y;
        vsumT[((size_t)k * 32 + o0 + 2) * 64 + b] = nv.z;
        vsumT[((size_t)k * 32 + o0 + 3) * 64 + b] = nv.w;
    }
    if (wout) *reinterpret_cast<float4*>(out + e0) = wv;
}

// ---------------- fallback kernels (raw f32 path) ----------------
template<int UF, int MODE>
__global__ __launch_bounds__(1024, 8)
void caps_mm32(const bf16* __restrict__ Xfrag, const bf16* __restrict__ Wfrag,
               const float* __restrict__ Xf, const float* __restrict__ Wf,
               const float* __restrict__ cbuf, bf16* __restrict__ partial, int Jc)
{
    const int tid  = threadIdx.x;
    const int w    = tid >> 6;
    const int lane = tid & 63;
    const int o31  = lane & 31;
    const int hi   = lane >> 5;
    int q, jr; decode_qjr(blockIdx.x, q, jr);
    const int unit = q * 16 + w;
    const int k    = unit & 31;
    const int c01  = unit >> 5;
    const int b    = c01 * 32 + o31;

    const f32x16 ZV16 = {};
    f32x16 acc = ZV16;

    const int j0 = jr * Jc;
    int jend = j0 + Jc; if (jend > JJ) jend = JJ;

    for (int j = j0; j < jend; ++j) {
        bf16x8 fx, fw;
        if constexpr (UF) {
            fx = *reinterpret_cast<const bf16x8*>(Xfrag + (((size_t)j * 2 + c01) * 64 + lane) * 8);
            fw = *reinterpret_cast<const bf16x8*>(Wfrag + (((size_t)j * 32 + k) * 64 + lane) * 8);
        } else {
            const float* xs = Xf + ((size_t)b * JJ + j) * DI + hi * 8;
#pragma unroll
            for (int e = 0; e < 8; ++e) fx[e] = (bf16)xs[e];
            const float* ws = Wf + (size_t)j * 16384 + (size_t)k * 512 + hi * 256 + o31;
#pragma unroll
            for (int e = 0; e < 8; ++e) fw[e] = (bf16)ws[e * 32];
        }
        if constexpr (MODE == 0) {
            acc = __builtin_amdgcn_mfma_f32_32x32x16_bf16(fw, fx, acc, 0, 0, 0);
        } else {
            float cw = cbuf[((size_t)j * 32 + k) * 64 + b];
            f32x16 h = __builtin_amdgcn_mfma_f32_32x32x16_bf16(fw, fx, ZV16, 0, 0, 0);
#pragma unroll
            for (int r = 0; r < 16; ++r) acc[r] += cw * h[r];
        }
    }

    const float esc = (MODE == 0) ? 0.03125f : 1.0f;
    bf16* pout = partial + (size_t)jr * (BB * NKO);
#pragma unroll
    for (int qq = 0; qq < 4; ++qq) {
        bf16x4 o4;
#pragma unroll
        for (int rr = 0; rr < 4; ++rr) o4[rr] = (bf16)(acc[qq * 4 + rr] * esc);
        *reinterpret_cast<bf16x4*>(pout + (((size_t)unit * 4 + qq) * 64 + lane) * 4) = o4;
    }
}

template<int UF>
__global__ __launch_bounds__(256, 6)
void caps_logits32(const bf16* __restrict__ Xfrag, const bf16* __restrict__ Wfrag,
                   const float* __restrict__ Xf, const float* __restrict__ Wf,
                   const float* __restrict__ vsum, float* __restrict__ cbuf)
{
    __shared__ float cl[2][64][33];

    const int tid  = threadIdx.x;
    const int w    = tid >> 6;
    const int lane = tid & 63;
    const int o31  = lane & 31;
    const int hi   = lane >> 5;
    const int jg   = decode_jg(blockIdx.x);
    const int j0   = jg * 2;
    const int jj   = w >> 1;
    const int c01  = w & 1;
    const int j    = j0 + jj;
    const int b    = c01 * 32 + o31;

    const f32x16 ZV16 = {};

    bf16x8 fx;
    if constexpr (UF) {
        fx = *reinterpret_cast<const bf16x8*>(Xfrag + (((size_t)j * 2 + c01) * 64 + lane) * 8);
    } else {
        const float* xs = Xf + ((size_t)b * JJ + j) * DI + hi * 8;
#pragma unroll
        for (int e = 0; e < 8; ++e) fx[e] = (bf16)xs[e];
    }

    const float* vb = vsum + (size_t)b * NKO + hi * 4;
    float lk[32];
#pragma unroll
    for (int k = 0; k < 32; ++k) {
        bf16x8 fw;
        if constexpr (UF) {
            fw = *reinterpret_cast<const bf16x8*>(Wfrag + (((size_t)j * 32 + k) * 64 + lane) * 8);
        } else {
            const float* ws = Wf + (size_t)j * 16384 + (size_t)k * 512 + hi * 256 + o31;
#pragma unroll
            for (int e = 0; e < 8; ++e) fw[e] = (bf16)ws[e * 32];
        }
        f32x16 h = __builtin_amdgcn_mfma_f32_32x32x16_bf16(fw, fx, ZV16, 0, 0, 0);
        float a = 0.f;
        const float* vk = vb + k * 32;
#pragma unroll
        for (int qq = 0; qq < 4; ++qq) {
            float4 v4 = *reinterpret_cast<const float4*>(vk + qq * 8);
            a += h[qq * 4 + 0] * v4.x + h[qq * 4 + 1] * v4.y
               + h[qq * 4 + 2] * v4.z + h[qq * 4 + 3] * v4.w;
        }
        a += __shfl_xor(a, 32, 64);
        lk[k] = a;
    }

    float mx = lk[0];
#pragma unroll
    for (int k = 1; k < 32; ++k) mx = fmaxf(mx, lk[k]);
    float sm = 0.f;
#pragma unroll
    for (int k = 0; k < 32; ++k) { lk[k] = __expf(lk[k] - mx); sm += lk[k]; }
    float inv = 1.0f / sm;

    if (hi == 0) {
#pragma unroll
        for (int k = 0; k < 32; ++k) cl[jj][b][k] = lk[k] * inv;
    }
    __syncthreads();

#pragma unroll
    for (int j2 = 0; j2 < 2; ++j2) {
#pragma unroll
        for (int i = 0; i < 8; ++i) {
            int idx = i * 256 + tid;
            int kk = idx >> 6, bb = idx & 63;
            cbuf[((size_t)(j0 + j2) * 32 + kk) * 64 + bb] = cl[j2][bb][kk];
        }
    }
}

extern "C" void kernel_launch(void* const* d_in, const int* in_sizes, int n_in,
                              void* d_out, int out_size, void* d_ws, size_t ws_size,
                              hipStream_t stream)
{
    const float* X  = (const float*)d_in[0];   // [64, 2048, 16] f32
    const float* Wg = (const float*)d_in[1];   // [2048, 32, 16, 32] f32
    float* out = (float*)d_out;                // [64, 32, 32] f32

    const size_t WFRAG_B = (size_t)JJ * 32 * 64 * 8 * 2;   // 67108864
    const size_t XFRAG_B = (size_t)JJ * 2 * 64 * 8 * 2;    // 4194304
    const size_t VS_B    = 65536ull * 4;                   // 262144
    const size_t VT_B    = 65536ull * 4;                   // 262144 (transposed copy)
    const size_t CB_B    = (size_t)BB * JJ * KC * 4;       // 16777216
    const size_t FIX_B   = VS_B + VT_B + CB_B;

    int P = 128;
    int useFrag = 1;
    bf16 *Wfrag = nullptr, *Xfrag = nullptr, *partial = nullptr;
    float *vsum = nullptr, *vsumT = nullptr, *cbuf = nullptr;

    char* p = (char*)d_ws;
    if (ws_size >= WFRAG_B + XFRAG_B + FIX_B + (size_t)P * 65536 * 2) {
        Wfrag = (bf16*)p;            p += WFRAG_B;
        Xfrag = (bf16*)p;            p += XFRAG_B;
    } else {
        useFrag = 0;
        size_t avail = (ws_size > FIX_B) ? (ws_size - FIX_B) / (65536 * 2) : 8;
        P = (int)(avail & ~7ull);    // multiple of 8 for the XCD swizzle
        if (P < 8) P = 8;
        if (P > 128) P = 128;
    }
    vsum    = (float*)p;  p += VS_B;
    vsumT   = (float*)p;  p += VT_B;
    cbuf    = (float*)p;  p += CB_B;
    partial = (bf16*)p;

    const int Jc = (JJ + P - 1) / P;

    if (useFrag) {
        prep_x3<<<dim3(1024), dim3(256), 0, stream>>>(X, Xfrag);

        // iter 0: fused W-prep + init (uniform c = 1/32)
        caps_init8<<<dim3(8 * P), dim3(512), 0, stream>>>(Xfrag, Wg, Wfrag, partial, Jc);
        caps_red<<<dim3(64), dim3(256), 0, stream>>>(partial, vsum, vsumT, out, P, 0, 0);

        // iter 1
        caps_logits8<<<dim3(1024), dim3(512), 0, stream>>>(Xfrag, Wfrag, vsumT, cbuf);
        caps_accum2<<<dim3(8 * P), dim3(512), 0, stream>>>(Xfrag, Wfrag, cbuf, partial, Jc);
        caps_red<<<dim3(64), dim3(256), 0, stream>>>(partial, vsum, vsumT, out, P, 1, 0);

        // iter 2 (writes output)
        caps_logits8<<<dim3(1024), dim3(512), 0, stream>>>(Xfrag, Wfrag, vsumT, cbuf);
        caps_accum2<<<dim3(8 * P), dim3(512), 0, stream>>>(Xfrag, Wfrag, cbuf, partial, Jc);
        caps_red<<<dim3(64), dim3(256), 0, stream>>>(partial, vsum, vsumT, out, P, 2, 1);
    } else {
        caps_mm32<0,0><<<dim3(4 * P), dim3(1024), 0, stream>>>(Xfrag, Wfrag, X, Wg, cbuf, partial, Jc);
        caps_red<<<dim3(64), dim3(256), 0, stream>>>(partial, vsum, vsumT, out, P, 0, 0);

        caps_logits32<0><<<dim3(1024), dim3(256), 0, stream>>>(Xfrag, Wfrag, X, Wg, vsum, cbuf);
        caps_mm32<0,1><<<dim3(4 * P), dim3(1024), 0, stream>>>(Xfrag, Wfrag, X, Wg, cbuf, partial, Jc);
        caps_red<<<dim3(64), dim3(256), 0, stream>>>(partial, vsum, vsumT, out, P, 1, 0);

        caps_logits32<0><<<dim3(1024), dim3(256), 0, stream>>>(Xfrag, Wfrag, X, Wg, vsum, cbuf);
        caps_mm32<0,1><<<dim3(4 * P), dim3(1024), 0, stream>>>(Xfrag, Wfrag, X, Wg, cbuf, partial, Jc);
        caps_red<<<dim3(64), dim3(256), 0, stream>>>(partial, vsum, vsumT, out, P, 2, 1);
    }
}